// Round 10
// baseline (1118.409 us; speedup 1.0000x reference)
//
#include <hip/hip_runtime.h>
#include <hip/hip_bf16.h>

// MolGAN discriminator: 3x RGCN(+BN over atom axis+LeakyReLU) + masked-sum readout.
// R10 = R9 with the REAL race fixed: sfinP was written by wave 0 only (tid<32) but read
// by all 4 waves in the phase-A staging loop BEFORE barrier 1 -> waves 1-3 raced wave 0's
// finPrev load and could read the previous resident block's LDS content (benign for
// same-layer neighbors -> usually passes; garbage after kernel switches -> R8's 14.45;
// timing-dependent -> R6/R9 tripwire). Fix: per-wave population (lane<32) -- same-wave
// DS is in-order, cross-wave writes are same-value/benign. Also hardened the only
// barrier-free type-punned LDS pair (xT park -> GEMM2 read) to a single short TBAA type.
// No atomics anywhere -> bitwise deterministic.

#define NB 32768
#define NA 9
#define NR 4
#define D0 5
#define D1 64
#define D2 128
#define D3 256
#define EPS 1e-5f
#define SLOPE 0.2f
#define NMOL 5
#define MR 48
#define NBLK ((NB + NMOL - 1) / NMOL)   // 6554

typedef __hip_bfloat16 bf16;
typedef short bf16x8 __attribute__((ext_vector_type(8)));
typedef float f32x4 __attribute__((ext_vector_type(4)));
typedef float f32x2 __attribute__((ext_vector_type(2)));

__device__ __forceinline__ float bf2f(bf16 v) { return __bfloat162float(v); }
__device__ __forceinline__ bf16  f2bf(float v) { return __float2bfloat16(v); }
__device__ __forceinline__ short f2bfs(float v) {
    union { bf16 b; short s; } u; u.b = __float2bfloat16(v); return u.s;
}

__device__ __forceinline__ void cvt8(bf16x8 v, f32x2 out[4]) {
    union { bf16x8 h; unsigned u[4]; } cv; cv.h = v;
    #pragma unroll
    for (int j = 0; j < 4; j++) {
        out[j].x = __uint_as_float(cv.u[j] << 16);
        out[j].y = __uint_as_float(cv.u[j] & 0xffff0000u);
    }
}

__device__ __forceinline__ bf16x8 pack8(const f32x2 y[4]) {
    union { bf16x8 h; unsigned short s[8]; } cv;
    #pragma unroll
    for (int j = 0; j < 4; j++) {
        union { bf16 b; unsigned short s; } t0, t1;
        t0.b = f2bf(y[j].x); t1.b = f2bf(y[j].y);
        cv.s[2*j] = t0.s; cv.s[2*j+1] = t1.s;
    }
    return cv.h;
}

// ---------------- weight prep: wt[s][n][k] bf16 ----------------
template<int DIN, int DOUT>
__global__ __launch_bounds__(256) void k_prep(const float* __restrict__ ws,
                                              const float* __restrict__ wr,
                                              bf16* __restrict__ wt)
{
    int idx = blockIdx.x*256 + threadIdx.x;
    if (idx >= 5*DOUT*DIN) return;
    int s = idx / (DOUT*DIN);
    int rem = idx % (DOUT*DIN);
    int n = rem / DIN, k = rem % DIN;
    float v = (s == 0) ? ws[(size_t)k*DOUT + n]
                       : wr[((size_t)(s-1)*DIN + k)*DOUT + n];
    wt[idx] = f2bf(v);
}

// ---------------- layer 0 (din=5) ----------------
__global__ __launch_bounds__(256) void k_layer0(
    const float* __restrict__ feats, const float* __restrict__ adj,
    const float* __restrict__ ws, const float* __restrict__ wr,
    const float* __restrict__ bias, bf16* __restrict__ hpre)
{
    __shared__ float Wsh[5][5][64];
    __shared__ float Bsh[64];
    __shared__ float Adj[4][4][9][9];
    __shared__ float Hsh[4][9][5];

    int tid = threadIdx.x;
    int bl  = tid >> 6;
    int e   = tid & 63;
    int b0  = blockIdx.x * 4;

    for (int i = tid; i < 5*64; i += 256) Wsh[0][i/64][i%64] = ws[i];
    for (int i = tid; i < 4*5*64; i += 256) {
        int s = i / 320, rem = i % 320;
        Wsh[1+s][rem/64][rem%64] = wr[i];
    }
    if (tid < 64) Bsh[tid] = bias[tid];
    {
        const float* ap = adj + (size_t)(b0 + bl) * (NR*NA*NA);
        float* dst = &Adj[bl][0][0][0];
        for (int i = e; i < NR*NA*NA; i += 64) dst[i] = ap[i];
    }
    {
        const float* fp = feats + (size_t)(b0 + bl) * (NA*D0);
        float* dst = &Hsh[bl][0][0];
        for (int i = e; i < NA*D0; i += 64) dst[i] = fp[i];
    }
    __syncthreads();

    float X[5][9];
    #pragma unroll
    for (int s = 0; s < 5; s++)
        #pragma unroll
        for (int n = 0; n < 9; n++) {
            float a = 0.f;
            #pragma unroll
            for (int k = 0; k < 5; k++) a += Hsh[bl][n][k] * Wsh[s][k][e];
            X[s][n] = a;
        }
    float bv = Bsh[e];
    bf16* hp = hpre + (size_t)(b0 + bl) * (NA*D1) + e;
    #pragma unroll
    for (int m = 0; m < 9; m++) {
        float a = X[0][m] + bv;
        #pragma unroll
        for (int r = 0; r < 4; r++)
            #pragma unroll
            for (int n = 0; n < 9; n++)
                a += Adj[bl][r][m][n] * X[1+r][n];
        hp[m*D1] = f2bf(a);
    }
}

// ---------------- deterministic stats over stored h ----------------
template<int D>
__global__ __launch_bounds__(256) void k_stats(const bf16* __restrict__ h,
                                               float2* __restrict__ sbuf)
{
    int g = blockIdx.x;   // 64 batch slices of 512 mols
    int a = blockIdx.y;   // atom
    int tid = threadIdx.x;
    constexpr int NIT = (512*D/8)/256;
    const bf16* base = h + ((size_t)g*512*NA + a)*D;
    float s = 0.f, q = 0.f;
    for (int it = 0; it < NIT; it++) {
        int i = (it*256 + tid)*8;
        int b = i / D, c = i % D;
        bf16x8 hv = *(const bf16x8*)(base + (size_t)b*NA*D + c);
        f32x2 hf[4]; cvt8(hv, hf);
        #pragma unroll
        for (int j = 0; j < 4; j++) {
            s += hf[j].x + hf[j].y;
            q += hf[j].x*hf[j].x + hf[j].y*hf[j].y;
        }
    }
    #pragma unroll
    for (int off = 1; off < 64; off <<= 1) {
        s += __shfl_xor(s, off, 64);
        q += __shfl_xor(q, off, 64);
    }
    __shared__ float ls[4], lq[4];
    if ((tid & 63) == 0) { ls[tid >> 6] = s; lq[tid >> 6] = q; }
    __syncthreads();
    if (tid == 0)
        sbuf[a*64 + g] = (float2){ls[0]+ls[1]+ls[2]+ls[3], lq[0]+lq[1]+lq[2]+lq[3]};
}

// ---------------- BN finalize from sbuf (fixed order) ----------------
template<int DOUT>
__global__ void k_finalize(const float2* __restrict__ sbuf,
                           const float* __restrict__ g, const float* __restrict__ be,
                           float* __restrict__ fin)
{
    int n = threadIdx.x;
    if (n < 9) {
        float s = 0.f, q = 0.f;
        for (int i = 0; i < 64; i++) { float2 v = sbuf[n*64 + i]; s += v.x; q += v.y; }
        float cnt = (float)NB * (float)DOUT;
        float mean = s / cnt;
        float var  = q / cnt - mean*mean;
        float sc   = g[n] * rsqrtf(var + EPS);
        fin[n]    = sc;
        fin[16+n] = be[n] - mean * sc;
    }
}

// ---------------- Path-B layer-2 finalize (fixed order) ----------------
__global__ __launch_bounds__(256) void k_finalize2(
    const float* __restrict__ pbS, const float* __restrict__ pbQ,
    const float* __restrict__ g, const float* __restrict__ be, float* __restrict__ fin)
{
    int a = blockIdx.x;   // 0..8
    int tid = threadIdx.x;
    float s = 0.f, q = 0.f;
    for (int i = tid; i < NBLK*4; i += 256) { s += pbS[(size_t)i*16 + a]; q += pbQ[(size_t)i*16 + a]; }
    #pragma unroll
    for (int off = 1; off < 64; off <<= 1) {
        s += __shfl_xor(s, off, 64);
        q += __shfl_xor(q, off, 64);
    }
    __shared__ float ls[4], lq[4];
    if ((tid & 63) == 0) { ls[tid >> 6] = s; lq[tid >> 6] = q; }
    __syncthreads();
    if (tid == 0) {
        float S = ls[0]+ls[1]+ls[2]+ls[3];
        float Q = lq[0]+lq[1]+lq[2]+lq[3];
        float cnt = (float)NB * (float)D3;
        float mean = S / cnt;
        float var  = Q / cnt - mean*mean;
        float sc   = g[a] * rsqrtf(var + EPS);
        fin[a]    = sc;
        fin[16+a] = be[a] - mean * sc;
    }
}

// ---------------- fused RGCN layer: transform-then-aggregate, all MFMA ----------------
// MODE 0: store hout.  MODE 1: per-block stat partials.  MODE 2: readout -> out4 slice.
template<int DIN, int DOUT, int MODE>
__global__ __launch_bounds__(256, 2) void k_fused(
    const bf16*  __restrict__ hprev,   // [B,9,DIN]
    const float* __restrict__ finPrev, // prev-layer BN affine [32]
    const float* __restrict__ adjg,    // [B,4,9,9]
    const bf16*  __restrict__ wt,      // [5][DOUT][DIN]
    const float* __restrict__ bias,    // [DOUT]
    bf16*  __restrict__ hout,          // (MODE 0)
    float* __restrict__ pbS,           // (MODE 1)
    float* __restrict__ pbQ,           // (MODE 1)
    const float* __restrict__ finC,    // (MODE 2)
    const float* __restrict__ maskg,   // (MODE 2)
    const float* __restrict__ fcw,     // (MODE 2)
    float* __restrict__ out4)          // (MODE 2) [4][NB]
{
    constexpr int HSP = DIN + 8;
    constexpr int SRP = 80;
    constexpr int XTP = 4*SRP + 8;     // 328
    constexpr int AP  = 72;
    constexpr int KK1 = DIN/32;
    constexpr int HW8 = DIN/8;

    __shared__ __align__(16) bf16  hS[MR*HSP];
    __shared__ __align__(16) short xT[64*XTP];      // [col][sec*SRP + mol*16 + n] (short TBAA)
    __shared__ __align__(16) bf16  adjB[NMOL*16*AP];
    __shared__ float aggL[64*45];                   // [col][mol*9 + atom]
    __shared__ float wsumS[4*48], wsumQ[4*48];
    __shared__ float rowS[48], rowQ[48];
    __shared__ float sfinP[32];
    __shared__ float sfinC2[32];

    int tid = threadIdx.x;
    int lane = tid & 63;
    int wv = tid >> 6;
    int mol_lo = blockIdx.x * NMOL;
    int nmol = NB - mol_lo; if (nmol > NMOL) nmol = NMOL;
    int nrow = nmol * 9;
    int cb = blockIdx.y * 64;

    // per-wave population: every wave writes the same values BEFORE its own reads
    // (same-wave DS in-order; cross-wave same-value writes benign). This was the
    // R6/R8/R9 race: tid<32 left waves 1-3 reading stale LDS pre-barrier.
    if (lane < 32) sfinP[lane] = finPrev[lane];
    if constexpr (MODE == 2) { if (lane >= 32) sfinC2[lane-32] = finC[lane-32]; }

    const bf16x8 z8 = (bf16x8){0,0,0,0,0,0,0,0};

    // ---- phase A ----
    for (int i = tid; i < 64*XTP/8; i += 256) ((bf16x8*)xT)[i] = z8;

    for (int i = tid; i < MR*HW8; i += 256) {
        int rl = i / HW8;
        int c8 = (i % HW8)*8;
        bf16x8 o8 = z8;
        if (rl < nrow) {
            bf16x8 hv = *(const bf16x8*)(hprev + (size_t)(mol_lo*9 + rl)*DIN + c8);
            f32x2 hf[4]; cvt8(hv, hf);
            int a = rl % 9;
            float sc = sfinP[a], sh = sfinP[16+a];
            f32x2 o[4];
            #pragma unroll
            for (int j = 0; j < 4; j++) {
                float v0 = sc*hf[j].x + sh; v0 = fmaxf(v0, SLOPE*v0);
                float v1 = sc*hf[j].y + sh; v1 = fmaxf(v1, SLOPE*v1);
                o[j] = (f32x2){v0, v1};
            }
            o8 = pack8(o);
        }
        *(bf16x8*)(&hS[rl*HSP + c8]) = o8;
    }

    for (int i = tid; i < NMOL*7*(AP/8); i += 256) {
        int molm = i / (AP/8);
        int c8 = (i % (AP/8))*8;
        int mol = molm / 7, m = 9 + molm % 7;
        *(bf16x8*)(&adjB[(mol*16 + m)*AP + c8]) = z8;
    }
    for (int i = tid; i < NMOL*9*4*7; i += 256) {
        int mol = i / 252;
        int t = i % 252;
        int m = t / 28;
        int u = t % 28;
        int r = u / 7, n = 9 + u % 7;
        adjB[(mol*16 + m)*AP + 16*r + n] = f2bf(0.f);
    }
    for (int i = tid; i < nmol*324; i += 256) {
        int mol = i / 324;
        int t = i % 324;
        int r = t / 81;
        int m = (t % 81) / 9;
        int n = t % 9;
        float v = adjg[(size_t)(mol_lo + mol)*324 + t];
        adjB[(mol*16 + m)*AP + 16*r + n] = f2bf(v);
    }
    __syncthreads();   // barrier 1

    int q = lane >> 4, l15 = lane & 15;
    int wl = wv*16 + l15;
    int wcol = cb + wl;

    // ---- GEMM1: X = act(h) @ [ws|wr0..3] ----
    f32x4 accS[3];
    f32x4 accR[4][3];
    #pragma unroll
    for (int mt = 0; mt < 3; mt++) accS[mt] = (f32x4){0.f,0.f,0.f,0.f};
    #pragma unroll
    for (int s = 0; s < 4; s++)
        #pragma unroll
        for (int mt = 0; mt < 3; mt++) accR[s][mt] = (f32x4){0.f,0.f,0.f,0.f};

    const bf16* wbase = wt + (size_t)wcol*DIN + q*8;
    #pragma unroll
    for (int kk = 0; kk < KK1; kk++) {
        bf16x8 Af[3];
        #pragma unroll
        for (int mt = 0; mt < 3; mt++)
            Af[mt] = *(const bf16x8*)(&hS[(mt*16 + l15)*HSP + kk*32 + q*8]);
        {
            bf16x8 Bf = *(const bf16x8*)(wbase + kk*32);
            #pragma unroll
            for (int mt = 0; mt < 3; mt++)
                accS[mt] = __builtin_amdgcn_mfma_f32_16x16x32_bf16(Af[mt], Bf, accS[mt], 0, 0, 0);
        }
        #pragma unroll
        for (int s = 0; s < 4; s++) {
            bf16x8 Bf = *(const bf16x8*)(wbase + (size_t)(s+1)*DOUT*DIN + kk*32);
            #pragma unroll
            for (int mt = 0; mt < 3; mt++)
                accR[s][mt] = __builtin_amdgcn_mfma_f32_16x16x32_bf16(Af[mt], Bf, accR[s][mt], 0, 0, 0);
        }
    }
    short* xcol = xT + (size_t)wl*XTP;
    #pragma unroll
    for (int s = 0; s < 4; s++)
        #pragma unroll
        for (int mt = 0; mt < 3; mt++)
            #pragma unroll
            for (int reg = 0; reg < 4; reg++) {
                int row = mt*16 + q*4 + reg;
                if (row < 45) {
                    int mu = row / 9, n = row % 9;
                    xcol[s*SRP + mu*16 + n] = f2bfs(accR[s][mt][reg]);
                }
            }

    // ---- GEMM2: agg = adjB @ Xstack (wave-private column set; no barrier) ----
    f32x4 accA[NMOL];
    for (int mu = 0; mu < nmol; mu++) {
        f32x4 acc = (f32x4){0.f,0.f,0.f,0.f};
        #pragma unroll
        for (int kk = 0; kk < 2; kk++) {
            int k0 = kk*32 + q*8;
            int rr = k0 >> 4;
            int n0 = k0 & 15;
            bf16x8 Af = *(const bf16x8*)(&adjB[((mu*16) + l15)*AP + k0]);
            bf16x8 Bf = *(const bf16x8*)(&xcol[rr*SRP + mu*16 + n0]);
            acc = __builtin_amdgcn_mfma_f32_16x16x32_bf16(Af, Bf, acc, 0, 0, 0);
        }
        accA[mu] = acc;
    }
    for (int mu = 0; mu < nmol; mu++) {
        #pragma unroll
        for (int reg = 0; reg < 4; reg++) {
            int atom = q*4 + reg;
            if (atom < 9) aggL[wl*45 + mu*9 + atom] = accA[mu][reg];
        }
    }

    // ---- epilogue ----
    float bcol = bias[wcol];

    if constexpr (MODE == 0) {
        #pragma unroll
        for (int mt = 0; mt < 3; mt++) {
            #pragma unroll
            for (int reg = 0; reg < 4; reg++) {
                int row = mt*16 + q*4 + reg;
                if (row < nrow) {
                    float v = accS[mt][reg] + aggL[wl*45 + row] + bcol;
                    hout[(size_t)(mol_lo*9 + row)*DOUT + wcol] = f2bf(v);
                }
            }
        }
        return;
    }

    if constexpr (MODE == 1) {
        #pragma unroll
        for (int mt = 0; mt < 3; mt++) {
            #pragma unroll
            for (int reg = 0; reg < 4; reg++) {
                int row = mt*16 + q*4 + reg;
                float s = 0.f, qq = 0.f;
                if (row < nrow) {
                    float v = accS[mt][reg] + aggL[wl*45 + row] + bcol;
                    s = v; qq = v*v;
                }
                s += __shfl_xor(s, 1); s += __shfl_xor(s, 2);
                s += __shfl_xor(s, 4); s += __shfl_xor(s, 8);
                qq += __shfl_xor(qq, 1); qq += __shfl_xor(qq, 2);
                qq += __shfl_xor(qq, 4); qq += __shfl_xor(qq, 8);
                if (l15 == 0) { wsumS[wv*48 + row] = s; wsumQ[wv*48 + row] = qq; }
            }
        }
        __syncthreads();
        if (tid < 48) {
            rowS[tid] = wsumS[tid] + wsumS[48+tid] + wsumS[96+tid] + wsumS[144+tid];
            rowQ[tid] = wsumQ[tid] + wsumQ[48+tid] + wsumQ[96+tid] + wsumQ[144+tid];
        }
        __syncthreads();
        if (tid < 9) {
            float sA = 0.f, qA = 0.f;
            #pragma unroll
            for (int mu = 0; mu < NMOL; mu++) { sA += rowS[mu*9 + tid]; qA += rowQ[mu*9 + tid]; }
            size_t pi = ((size_t)blockIdx.y*NBLK + blockIdx.x)*16 + tid;
            pbS[pi] = sA;
            pbQ[pi] = qA;
        }
        return;
    }

    // MODE 2: fused BN + leaky + mask + fc readout -> out4 slice
    {
        float fw = fcw[wcol];
        #pragma unroll
        for (int mt = 0; mt < 3; mt++) {
            #pragma unroll
            for (int reg = 0; reg < 4; reg++) {
                int row = mt*16 + q*4 + reg;
                float part = 0.f;
                if (row < nrow) {
                    int atom = row % 9;
                    float v = accS[mt][reg] + aggL[wl*45 + row] + bcol;
                    float y = sfinC2[atom]*v + sfinC2[16+atom];
                    y = fmaxf(y, SLOPE*y);
                    part = y * fw;
                }
                part += __shfl_xor(part, 1); part += __shfl_xor(part, 2);
                part += __shfl_xor(part, 4); part += __shfl_xor(part, 8);
                if (l15 == 0) wsumS[wv*48 + row] = part;
            }
        }
        __syncthreads();
        if (tid < nrow)
            rowS[tid] = (wsumS[tid] + wsumS[48+tid] + wsumS[96+tid] + wsumS[144+tid])
                        * maskg[(size_t)mol_lo*9 + tid];
        __syncthreads();
        if (tid < nmol) {
            float t = 0.f;
            #pragma unroll
            for (int j = 0; j < 9; j++) t += rowS[tid*9 + j];
            out4[(size_t)blockIdx.y*NB + mol_lo + tid] = t;
        }
    }
}

// ---------------- Path-A readout ----------------
__global__ __launch_bounds__(256) void k_readout(
    const bf16* __restrict__ h2, const float* __restrict__ fin,
    const float* __restrict__ mask, const float* __restrict__ fcw,
    const float* __restrict__ fcb, float* __restrict__ out)
{
    int tid = threadIdx.x;
    int w = tid >> 6, lane = tid & 63;
    int b = blockIdx.x * 4 + w;
    float sc[9], sh[9];
    #pragma unroll
    for (int n = 0; n < 9; n++) { sc[n] = fin[n]; sh[n] = fin[16+n]; }
    const bf16* hp = h2 + (size_t)b * (NA*D3) + lane*4;
    float acc0 = 0.f, acc1 = 0.f, acc2 = 0.f, acc3 = 0.f;
    #pragma unroll
    for (int n = 0; n < 9; n++) {
        bf16 v4[4] __attribute__((aligned(8)));
        *(uint2*)v4 = *(const uint2*)(hp + n*D3);
        float mk = mask[(size_t)b*NA + n];
        float v;
        v = sc[n]*bf2f(v4[0]) + sh[n]; v = fmaxf(v, SLOPE*v); acc0 += v*mk;
        v = sc[n]*bf2f(v4[1]) + sh[n]; v = fmaxf(v, SLOPE*v); acc1 += v*mk;
        v = sc[n]*bf2f(v4[2]) + sh[n]; v = fmaxf(v, SLOPE*v); acc2 += v*mk;
        v = sc[n]*bf2f(v4[3]) + sh[n]; v = fmaxf(v, SLOPE*v); acc3 += v*mk;
    }
    float4 wvv = *(const float4*)(fcw + lane*4);
    float s = acc0*wvv.x + acc1*wvv.y + acc2*wvv.z + acc3*wvv.w;
    #pragma unroll
    for (int off = 1; off < 64; off <<= 1) s += __shfl_xor(s, off, 64);
    if (lane == 0) out[b] = s + fcb[0];
}

// Path-B final: fixed-order sum of 4 slices + fcb
__global__ __launch_bounds__(256) void k_sum4(float* __restrict__ out,
                                              const float* __restrict__ out4,
                                              const float* __restrict__ fcb)
{
    int idx = blockIdx.x * 256 + threadIdx.x;
    if (idx < NB)
        out[idx] = out4[idx] + out4[NB+idx] + out4[2*NB+idx] + out4[3*NB+idx] + fcb[0];
}

// ---------------- workspace layout (bytes) ----------------
// [0, 13824)        : sbuf float2[3][9][64]
// [16384, 16768)    : fins 3 x 32 fp32
// [32768, 114688)   : wt1 bf16 [5][128][64]
// [114688, 442368)  : wt2 bf16 [5][256][128]
// [442368, 966656)  : out4 fp32 [4][NB]           (Path B)
// [966656, 2644480) : pbS fp32 [NBLK*4][16]       (Path B)
// [2644480, 4322304): pbQ fp32 [NBLK*4][16]       (Path B)
// Path A: h1 @4718592 (75,497,472); h2 @80216064 (150,994,944); h0 aliased at h2 base
//         (dead before first h2 write). End = 231,211,008.
// Path B: h0 @4718592 (37,748,736); h1 @42467328 (75,497,472). End = 117,964,800.

extern "C" void kernel_launch(void* const* d_in, const int* in_sizes, int n_in,
                              void* d_out, int out_size, void* d_ws, size_t ws_size,
                              hipStream_t stream)
{
    const float* feats = (const float*)d_in[0];
    const float* adj   = (const float*)d_in[1];
    const float* mask  = (const float*)d_in[2];
    const float* ws0 = (const float*)d_in[3];
    const float* wr0 = (const float*)d_in[4];
    const float* b0  = (const float*)d_in[5];
    const float* g0  = (const float*)d_in[6];
    const float* be0 = (const float*)d_in[7];
    const float* ws1 = (const float*)d_in[8];
    const float* wr1 = (const float*)d_in[9];
    const float* b1  = (const float*)d_in[10];
    const float* g1  = (const float*)d_in[11];
    const float* be1 = (const float*)d_in[12];
    const float* ws2 = (const float*)d_in[13];
    const float* wr2 = (const float*)d_in[14];
    const float* b2  = (const float*)d_in[15];
    const float* g2  = (const float*)d_in[16];
    const float* be2 = (const float*)d_in[17];
    const float* fcw = (const float*)d_in[18];
    const float* fcb = (const float*)d_in[19];
    float* outp = (float*)d_out;

    char* wsb = (char*)d_ws;
    float2* sbuf0 = (float2*)(wsb + 0);
    float2* sbuf1 = sbuf0 + 576;
    float2* sbuf2 = sbuf1 + 576;
    float* fin0 = (float*)(wsb + 16384);
    float* fin1 = fin0 + 32;
    float* fin2 = fin1 + 32;
    bf16* wt1 = (bf16*)(wsb + 32768);
    bf16* wt2 = (bf16*)(wsb + 114688);
    float* out4 = (float*)(wsb + 442368);
    float* pbS  = (float*)(wsb + 966656);
    float* pbQ  = (float*)(wsb + 2644480);

    k_prep<D1, D2><<<(5*D2*D1 + 255)/256, 256, 0, stream>>>(ws1, wr1, wt1);
    k_prep<D2, D3><<<(5*D3*D2 + 255)/256, 256, 0, stream>>>(ws2, wr2, wt2);

    bool bigws = (ws_size >= 231211008ULL);
    dim3 sgrid(64, 9);
    dim3 g1d(NBLK, D2/64);
    dim3 g2d(NBLK, D3/64);

    if (bigws) {
        bf16* h1 = (bf16*)(wsb + 4718592ULL);
        bf16* h2 = (bf16*)(wsb + 80216064ULL);
        bf16* h0 = h2;   // alias: fully consumed before first h2 write

        k_layer0<<<NB/4, 256, 0, stream>>>(feats, adj, ws0, wr0, b0, h0);
        k_stats<D1><<<sgrid, 256, 0, stream>>>(h0, sbuf0);
        k_finalize<D1><<<1, 64, 0, stream>>>(sbuf0, g0, be0, fin0);

        k_fused<D1, D2, 0><<<g1d, 256, 0, stream>>>(
            h0, fin0, adj, wt1, b1, h1, nullptr, nullptr, nullptr, nullptr, nullptr, nullptr);
        k_stats<D2><<<sgrid, 256, 0, stream>>>(h1, sbuf1);
        k_finalize<D2><<<1, 64, 0, stream>>>(sbuf1, g1, be1, fin1);

        k_fused<D2, D3, 0><<<g2d, 256, 0, stream>>>(
            h1, fin1, adj, wt2, b2, h2, nullptr, nullptr, nullptr, nullptr, nullptr, nullptr);
        k_stats<D3><<<sgrid, 256, 0, stream>>>(h2, sbuf2);
        k_finalize<D3><<<1, 64, 0, stream>>>(sbuf2, g2, be2, fin2);

        k_readout<<<NB/4, 256, 0, stream>>>(h2, fin2, mask, fcw, fcb, outp);
    } else {
        bf16* h0 = (bf16*)(wsb + 4718592ULL);
        bf16* h1 = (bf16*)(wsb + 42467328ULL);

        k_layer0<<<NB/4, 256, 0, stream>>>(feats, adj, ws0, wr0, b0, h0);
        k_stats<D1><<<sgrid, 256, 0, stream>>>(h0, sbuf0);
        k_finalize<D1><<<1, 64, 0, stream>>>(sbuf0, g0, be0, fin0);

        k_fused<D1, D2, 0><<<g1d, 256, 0, stream>>>(
            h0, fin0, adj, wt1, b1, h1, nullptr, nullptr, nullptr, nullptr, nullptr, nullptr);
        k_stats<D2><<<sgrid, 256, 0, stream>>>(h1, sbuf1);
        k_finalize<D2><<<1, 64, 0, stream>>>(sbuf1, g1, be1, fin1);

        k_fused<D2, D3, 1><<<g2d, 256, 0, stream>>>(
            h1, fin1, adj, wt2, b2, nullptr, pbS, pbQ, nullptr, nullptr, nullptr, nullptr);
        k_finalize2<<<9, 256, 0, stream>>>(pbS, pbQ, g2, be2, fin2);

        k_fused<D2, D3, 2><<<g2d, 256, 0, stream>>>(
            h1, fin1, adj, wt2, b2, nullptr, nullptr, nullptr, fin2, mask, fcw, out4);
        k_sum4<<<(NB+255)/256, 256, 0, stream>>>(outp, out4, fcb);
    }
}